// Round 3
// baseline (283.571 us; speedup 1.0000x reference)
//
#include <hip/hip_runtime.h>
#include <math.h>

#define BB   64
#define NN   1024
#define FIN  16
#define DIM  64
#define KK   20
#define EPSV 1e-5f
#define SLOPE 0.2f
#define BN_COUNT (BB*NN)

__device__ inline float wred_sum(float v){
  #pragma unroll
  for (int m = 32; m > 0; m >>= 1) v += __shfl_xor(v, m, 64);
  return v;
}

// ---------------- kA: norms + emb·att_em_i / emb·att_em_j ----------------
__global__ void kA(const float* __restrict__ emb,
                   const float* __restrict__ att_em_i,
                   const float* __restrict__ att_em_j,
                   float* __restrict__ nrm, float* __restrict__ e_i, float* __restrict__ e_j){
  int n = blockIdx.x, d = threadIdx.x;
  float v = emb[n*DIM + d];
  float ss = wred_sum(v*v);
  float di = wred_sum(v*att_em_i[d]);
  float dj = wred_sum(v*att_em_j[d]);
  if (d == 0){ nrm[n] = sqrtf(ss); e_i[n] = di; e_j[n] = dj; }
}

// ---------------- kB: per-row cosine + top-20 (lax.top_k semantics) ------
// Cosine phase: 256 threads. Selection phase: wave 0 with all 1024 values
// register-resident (16/lane); 20 rounds of local scan + butterfly argmax.
__global__ void kB(const float* __restrict__ emb, const float* __restrict__ nrm,
                   int* __restrict__ topk){
  __shared__ float cosv[NN];
  __shared__ __align__(16) float embi[DIM];
  int i = blockIdx.x, t = threadIdx.x;
  if (t < DIM) embi[t] = emb[i*DIM + t];
  __syncthreads();
  float ni = nrm[i];
  int g = t >> 4, l16 = t & 15;
  const float4* e4 = (const float4*)emb;
  float4 a4 = ((const float4*)embi)[l16];
  for (int jb = 0; jb < NN; jb += 16){
    int j = jb + g;
    float4 b4 = e4[j*(DIM/4) + l16];
    float p = a4.x*b4.x + a4.y*b4.y + a4.z*b4.z + a4.w*b4.w;
    p += __shfl_xor(p, 1, 64); p += __shfl_xor(p, 2, 64);
    p += __shfl_xor(p, 4, 64); p += __shfl_xor(p, 8, 64);
    if (l16 == 0) cosv[j] = p / (ni * nrm[j]);
  }
  __syncthreads();
  if (t < 64){
    float c[16];
    #pragma unroll
    for (int q = 0; q < 4; q++){
      float4 v = ((const float4*)cosv)[t*4 + q];
      c[q*4+0] = v.x; c[q*4+1] = v.y; c[q*4+2] = v.z; c[q*4+3] = v.w;
    }
    #pragma unroll 1
    for (int k = 0; k < KK; k++){
      float bv = c[0]; int bm = 0;
      #pragma unroll
      for (int m = 1; m < 16; m++){
        if (c[m] > bv){ bv = c[m]; bm = m; }   // strict > : lowest m wins ties
      }
      int bj = t*16 + bm;
      #pragma unroll
      for (int msk = 32; msk > 0; msk >>= 1){
        float pv = __shfl_xor(bv, msk, 64);
        int   pj = __shfl_xor(bj, msk, 64);
        if (pv > bv || (pv == bv && pj < bj)){ bv = pv; bj = pj; }
      }
      if (t == 0) topk[i*KK + k] = bj;
      #pragma unroll
      for (int m = 0; m < 16; m++){
        c[m] = (bj == t*16 + m) ? -1e30f : c[m];  // kill winner
      }
    }
  }
}

// ---------------- kC: h = data @ lin_w^T ; s_i, s_j ----------------------
// 16 rows per block staged in LDS; per-row input values come from LDS
// broadcast reads (no shuffles on the matmul side).
__global__ void kC(const float* __restrict__ data, const float* __restrict__ lin_w,
                   const float* __restrict__ att_i, const float* __restrict__ att_j,
                   const float* __restrict__ e_i, const float* __restrict__ e_j,
                   float* __restrict__ h, float* __restrict__ s_i, float* __restrict__ s_j){
  __shared__ float lw[FIN*DIM];              // lw[f*64+d]
  __shared__ __align__(16) float sd[16][FIN];
  int t = threadIdx.x;
  for (int u = t; u < FIN*DIM; u += 256){
    int d = u >> 4, f = u & 15;
    lw[f*DIM + d] = lin_w[u];
  }
  int r0 = blockIdx.x*16;
  sd[t >> 4][t & 15] = data[r0*FIN + t];     // 256 floats, coalesced
  __syncthreads();
  int wave = t >> 6, lane = t & 63;
  float ai = att_i[lane], aj = att_j[lane];
  #pragma unroll
  for (int q = 0; q < 4; q++){
    int row = wave*4 + q;
    int r = r0 + row;
    int n = r & (NN-1);
    float acc = 0.f;
    #pragma unroll
    for (int f4 = 0; f4 < 4; f4++){
      float4 d4 = ((const float4*)sd[row])[f4];   // broadcast read
      acc += d4.x * lw[(f4*4+0)*DIM + lane];
      acc += d4.y * lw[(f4*4+1)*DIM + lane];
      acc += d4.z * lw[(f4*4+2)*DIM + lane];
      acc += d4.w * lw[(f4*4+3)*DIM + lane];
    }
    h[r*DIM + lane] = acc;
    float si = wred_sum(acc * ai);
    float sj = wred_sum(acc * aj);
    if (lane == 0){ s_i[r] = si + e_i[n]; s_j[r] = sj + e_j[n]; }
  }
}

// ------- kD: softmax over K + gather aggregation + BN1 stats -------------
// XCD-swizzled (b % 8 == blockIdx % 8 -> 2 MB working set per XCD L2).
// All per-row softmax math is wave-uniform scalar work (no cross-lane ops);
// the 20 gathers are issued into a register array so they pipeline.
__global__ __launch_bounds__(256, 4)
void kD(const float* __restrict__ h, const float* __restrict__ s_i,
        const float* __restrict__ s_j, const int* __restrict__ topk,
        const float* __restrict__ gnn_bias,
        float* __restrict__ outp, float* __restrict__ acc){
  __shared__ float chs[DIM], chq[DIM];
  int t = threadIdx.x, wave = t >> 6, lane = t & 63;
  if (t < DIM){ chs[t] = 0.f; chq[t] = 0.f; }
  __syncthreads();
  int p = blockIdx.x;
  int xcd = p & 7, slot = p >> 3;
  int b = xcd + 8*(slot >> 5);     // 8 batches per XCD
  int chunk = slot & 31;
  float gb = gnn_bias[lane];
  float psum = 0.f, psq = 0.f;
  int n0 = chunk*32 + wave*8;
  const float* hb  = h   + (size_t)b * NN * DIM;
  const float* sjb = s_j + (size_t)b * NN;
  const float* sib = s_i + (size_t)b * NN;
  #pragma unroll 1
  for (int i = 0; i < 8; i++){
    int nu = __builtin_amdgcn_readfirstlane(n0 + i);
    float s_iv = sib[nu];
    int jv[KK];
    #pragma unroll
    for (int k = 0; k < KK; k++) jv[k] = topk[nu*KK + k];
    float xv[KK];
    #pragma unroll
    for (int k = 0; k < KK; k++){
      float x = s_iv + sjb[jv[k]];
      xv[k] = (x > 0.f) ? x : SLOPE * x;
    }
    float m = xv[0];
    #pragma unroll
    for (int k = 1; k < KK; k++) m = fmaxf(m, xv[k]);
    float ssum = 0.f;
    #pragma unroll
    for (int k = 0; k < KK; k++){ xv[k] = __expf(xv[k] - m); ssum += xv[k]; }
    float rs = 1.f / ssum;
    float gth[KK];
    #pragma unroll
    for (int k = 0; k < KK; k++) gth[k] = hb[jv[k]*DIM + lane];
    float o = 0.f;
    #pragma unroll
    for (int k = 0; k < KK; k++) o += (xv[k]*rs) * gth[k];
    o += gb;
    outp[((size_t)b*NN + nu)*DIM + lane] = o;
    psum += o; psq += o*o;
  }
  atomicAdd(&chs[lane], psum);
  atomicAdd(&chq[lane], psq);
  __syncthreads();
  if (t < DIM){ atomicAdd(&acc[t], chs[t]); atomicAdd(&acc[64+t], chq[t]); }
}

// ------- kF: BN1 finalize+apply + relu + *emb -> rep ; BN2 stats ---------
__global__ void kF(const float* __restrict__ outp, const float* __restrict__ emb,
                   const float* __restrict__ acc, const float* __restrict__ bn1_g,
                   const float* __restrict__ bn1_b, float* __restrict__ rep,
                   float* __restrict__ acc2){
  __shared__ float chs[DIM], chq[DIM];
  int t = threadIdx.x;
  if (t < DIM){ chs[t] = 0.f; chq[t] = 0.f; }
  __syncthreads();
  int cbase = (t*4) & 63;
  float4 sc, bs;
  {
    const float inv = 1.f / BN_COUNT;
    float m0 = acc[cbase+0]*inv, m1 = acc[cbase+1]*inv, m2 = acc[cbase+2]*inv, m3 = acc[cbase+3]*inv;
    float v0 = acc[64+cbase+0]*inv - m0*m0, v1 = acc[64+cbase+1]*inv - m1*m1;
    float v2 = acc[64+cbase+2]*inv - m2*m2, v3 = acc[64+cbase+3]*inv - m3*m3;
    sc.x = bn1_g[cbase+0]*rsqrtf(v0+EPSV); sc.y = bn1_g[cbase+1]*rsqrtf(v1+EPSV);
    sc.z = bn1_g[cbase+2]*rsqrtf(v2+EPSV); sc.w = bn1_g[cbase+3]*rsqrtf(v3+EPSV);
    bs.x = bn1_b[cbase+0] - m0*sc.x; bs.y = bn1_b[cbase+1] - m1*sc.y;
    bs.z = bn1_b[cbase+2] - m2*sc.z; bs.w = bn1_b[cbase+3] - m3*sc.w;
  }
  float s0=0,s1=0,s2=0,s3=0,q0=0,q1=0,q2=0,q3=0;
  const float4* op4 = (const float4*)outp;
  const float4* em4 = (const float4*)emb;
  float4* rp4 = (float4*)rep;
  const int total = BB*NN*DIM/4;
  for (int e = blockIdx.x*256 + t; e < total; e += 2048*256){
    float4 x = op4[e];
    float4 em = em4[e & (NN*DIM/4 - 1)];
    float4 y;
    y.x = fmaxf(x.x*sc.x + bs.x, 0.f) * em.x;
    y.y = fmaxf(x.y*sc.y + bs.y, 0.f) * em.y;
    y.z = fmaxf(x.z*sc.z + bs.z, 0.f) * em.z;
    y.w = fmaxf(x.w*sc.w + bs.w, 0.f) * em.w;
    rp4[e] = y;
    s0 += y.x; q0 += y.x*y.x;
    s1 += y.y; q1 += y.y*y.y;
    s2 += y.z; q2 += y.z*y.z;
    s3 += y.w; q3 += y.w*y.w;
  }
  atomicAdd(&chs[cbase+0], s0); atomicAdd(&chq[cbase+0], q0);
  atomicAdd(&chs[cbase+1], s1); atomicAdd(&chq[cbase+1], q1);
  atomicAdd(&chs[cbase+2], s2); atomicAdd(&chq[cbase+2], q2);
  atomicAdd(&chs[cbase+3], s3); atomicAdd(&chq[cbase+3], q3);
  __syncthreads();
  if (t < DIM){ atomicAdd(&acc2[t], chs[t]); atomicAdd(&acc2[64+t], chq[t]); }
}

// ------- kH: BN2 finalize+apply + relu + dot(out_w) -> fore --------------
__global__ void kH(const float* __restrict__ rep, const float* __restrict__ acc2,
                   const float* __restrict__ bn2_g, const float* __restrict__ bn2_b,
                   const float* __restrict__ out_w, const float* __restrict__ out_b,
                   float* __restrict__ out){
  int t = threadIdx.x, wave = t >> 6, lane = t & 63;
  int c16 = lane & 15, rsub = lane >> 4;
  int cb = c16*4;
  float4 sc, bs;
  {
    const float inv = 1.f / BN_COUNT;
    float m0 = acc2[cb+0]*inv, m1 = acc2[cb+1]*inv, m2 = acc2[cb+2]*inv, m3 = acc2[cb+3]*inv;
    float v0 = acc2[64+cb+0]*inv - m0*m0, v1 = acc2[64+cb+1]*inv - m1*m1;
    float v2 = acc2[64+cb+2]*inv - m2*m2, v3 = acc2[64+cb+3]*inv - m3*m3;
    sc.x = bn2_g[cb+0]*rsqrtf(v0+EPSV); sc.y = bn2_g[cb+1]*rsqrtf(v1+EPSV);
    sc.z = bn2_g[cb+2]*rsqrtf(v2+EPSV); sc.w = bn2_g[cb+3]*rsqrtf(v3+EPSV);
    bs.x = bn2_b[cb+0] - m0*sc.x; bs.y = bn2_b[cb+1] - m1*sc.y;
    bs.z = bn2_b[cb+2] - m2*sc.z; bs.w = bn2_b[cb+3] - m3*sc.w;
  }
  float4 w4 = *(const float4*)(out_w + cb);
  float ob = out_b[0];
  int rbase = blockIdx.x*64 + wave*16;
  for (int i = 0; i < 16; i += 4){
    int r = rbase + i + rsub;
    float4 x = *(const float4*)(rep + (size_t)r*DIM + cb);
    float p = fmaxf(x.x*sc.x + bs.x, 0.f) * w4.x
            + fmaxf(x.y*sc.y + bs.y, 0.f) * w4.y
            + fmaxf(x.z*sc.z + bs.z, 0.f) * w4.z
            + fmaxf(x.w*sc.w + bs.w, 0.f) * w4.w;
    p += __shfl_xor(p, 1, 64); p += __shfl_xor(p, 2, 64);
    p += __shfl_xor(p, 4, 64); p += __shfl_xor(p, 8, 64);
    if (c16 == 0) out[r] = p + ob;
  }
}

extern "C" void kernel_launch(void* const* d_in, const int* in_sizes, int n_in,
                              void* d_out, int out_size, void* d_ws, size_t ws_size,
                              hipStream_t stream) {
  const float* data     = (const float*)d_in[0];
  // d_in[1] org_edge_index: unused by the reference computation
  const float* emb      = (const float*)d_in[2];
  const float* lin_w    = (const float*)d_in[3];
  const float* att_i    = (const float*)d_in[4];
  const float* att_j    = (const float*)d_in[5];
  const float* att_em_i = (const float*)d_in[6];
  const float* att_em_j = (const float*)d_in[7];
  const float* gnn_bias = (const float*)d_in[8];
  const float* bn1_g    = (const float*)d_in[9];
  const float* bn1_b    = (const float*)d_in[10];
  const float* bn2_g    = (const float*)d_in[11];
  const float* bn2_b    = (const float*)d_in[12];
  const float* out_w    = (const float*)d_in[13];
  const float* out_b    = (const float*)d_in[14];
  float* out = (float*)d_out;

  float* ws   = (float*)d_ws;
  float* h    = ws;                        // 4194304 floats (aliased by rep later)
  float* outp = ws + 4194304;              // 4194304
  float* s_i  = ws + 8388608;              // 65536
  float* s_j  = s_i + 65536;               // 65536
  float* e_i  = s_j + 65536;               // 1024
  float* e_j  = e_i + NN;                  // 1024
  float* nrmv = e_j + NN;                  // 1024
  int*   topk = (int*)(nrmv + NN);         // 20480 ints
  float* acc  = (float*)(topk + NN*KK);    // 256 floats (bn1 sum/sq, bn2 sum/sq)
  float* rep  = h;                         // alias: h is dead after kD

  hipMemsetAsync(acc, 0, 256*sizeof(float), stream);
  kA<<<NN, 64, 0, stream>>>(emb, att_em_i, att_em_j, nrmv, e_i, e_j);
  kB<<<NN, 256, 0, stream>>>(emb, nrmv, topk);
  kC<<<(BB*NN)/16, 256, 0, stream>>>(data, lin_w, att_i, att_j, e_i, e_j, h, s_i, s_j);
  kD<<<(BB*NN)/32, 256, 0, stream>>>(h, s_i, s_j, topk, gnn_bias, outp, acc);
  kF<<<2048, 256, 0, stream>>>(outp, emb, acc, bn1_g, bn1_b, rep, acc + 128);
  kH<<<NN, 256, 0, stream>>>(rep, acc + 128, bn2_g, bn2_b, out_w, out_b, out);
}

// Round 4
// 244.152 us; speedup vs baseline: 1.1615x; 1.1615x over previous
//
#include <hip/hip_runtime.h>
#include <math.h>

#define BB   64
#define NN   1024
#define FIN  16
#define DIM  64
#define KK   20
#define EPSV 1e-5f
#define SLOPE 0.2f
#define BN_COUNT (BB*NN)
#define REPS 16

__device__ inline float wred_sum(float v){
  #pragma unroll
  for (int m = 32; m > 0; m >>= 1) v += __shfl_xor(v, m, 64);
  return v;
}

// ---------------- kA: inverse norms ----------------
__global__ void kA(const float* __restrict__ emb, float* __restrict__ inr){
  int n = blockIdx.x, d = threadIdx.x;
  float v = emb[n*DIM + d];
  float ss = wred_sum(v*v);
  if (d == 0) inr[n] = 1.f / sqrtf(ss);
}

// ---------------- kB: cosine row + top-20 (lax.top_k semantics) ----------
__global__ void kB(const float* __restrict__ emb, const float* __restrict__ inr,
                   int* __restrict__ topk){
  __shared__ float cosv[NN];
  __shared__ __align__(16) float embi[DIM];
  int i = blockIdx.x, t = threadIdx.x;
  if (t < DIM) embi[t] = emb[i*DIM + t];
  __syncthreads();
  float ri = inr[i];
  int g = t >> 4, l16 = t & 15;
  const float4* e4 = (const float4*)emb;
  float4 a4 = ((const float4*)embi)[l16];
  for (int jb = 0; jb < NN; jb += 16){
    int j = jb + g;
    float4 b4 = e4[j*(DIM/4) + l16];
    float p = a4.x*b4.x + a4.y*b4.y + a4.z*b4.z + a4.w*b4.w;
    p += __shfl_xor(p, 1, 64); p += __shfl_xor(p, 2, 64);
    p += __shfl_xor(p, 4, 64); p += __shfl_xor(p, 8, 64);
    if (l16 == 0) cosv[j] = p * ri * inr[j];
  }
  __syncthreads();
  if (t < 64){
    float c[16];
    #pragma unroll
    for (int q = 0; q < 4; q++){
      float4 v = ((const float4*)cosv)[t*4 + q];
      c[q*4+0] = v.x; c[q*4+1] = v.y; c[q*4+2] = v.z; c[q*4+3] = v.w;
    }
    #pragma unroll 1
    for (int k = 0; k < KK; k++){
      float bv = c[0]; int bm = 0;
      #pragma unroll
      for (int m = 1; m < 16; m++){
        if (c[m] > bv){ bv = c[m]; bm = m; }   // strict > : lowest idx wins ties
      }
      int bj = t*16 + bm;
      #pragma unroll
      for (int msk = 32; msk > 0; msk >>= 1){
        float pv = __shfl_xor(bv, msk, 64);
        int   pj = __shfl_xor(bj, msk, 64);
        if (pv > bv || (pv == bv && pj < bj)){ bv = pv; bj = pj; }
      }
      if (t == 0) topk[i*KK + k] = bj;
      #pragma unroll
      for (int m = 0; m < 16; m++){
        c[m] = (bj == t*16 + m) ? -1e30f : c[m];
      }
    }
  }
}

// ---------------- kC: h = data @ lin_w^T ; s_i, s_j (incl. emb terms) ----
__global__ void kC(const float* __restrict__ data, const float* __restrict__ lin_w,
                   const float* __restrict__ att_i, const float* __restrict__ att_j,
                   const float* __restrict__ att_em_i, const float* __restrict__ att_em_j,
                   const float* __restrict__ emb,
                   float* __restrict__ h, float* __restrict__ s_i, float* __restrict__ s_j){
  __shared__ float lw[FIN*DIM];              // lw[f*64+d]
  __shared__ __align__(16) float sd[16][FIN];
  int t = threadIdx.x;
  for (int u = t; u < FIN*DIM; u += 256){
    int d = u >> 4, f = u & 15;
    lw[f*DIM + d] = lin_w[u];
  }
  int r0 = blockIdx.x*16;
  sd[t >> 4][t & 15] = data[r0*FIN + t];
  __syncthreads();
  int wave = t >> 6, lane = t & 63;
  float ai = att_i[lane], aj = att_j[lane];
  float aemi = att_em_i[lane], aemj = att_em_j[lane];
  #pragma unroll
  for (int q = 0; q < 4; q++){
    int row = wave*4 + q;
    int r = r0 + row;
    int n = r & (NN-1);
    float acc = 0.f;
    #pragma unroll
    for (int f4 = 0; f4 < 4; f4++){
      float4 d4 = ((const float4*)sd[row])[f4];
      acc += d4.x * lw[(f4*4+0)*DIM + lane];
      acc += d4.y * lw[(f4*4+1)*DIM + lane];
      acc += d4.z * lw[(f4*4+2)*DIM + lane];
      acc += d4.w * lw[(f4*4+3)*DIM + lane];
    }
    h[r*DIM + lane] = acc;
    float ev = emb[n*DIM + lane];
    float si = wred_sum(acc*ai + ev*aemi);
    float sj = wred_sum(acc*aj + ev*aemj);
    if (lane == 0){ s_i[r] = si; s_j[r] = sj; }
  }
}

// ------- kD: softmax over K + float4 gather + BN1 stats (16-rep) ---------
// lane = rs(row-slot, lane>>4) x cg(channel-group, lane&15); wave = 4 rows.
// XCD-swizzled so each XCD's h working set is 8 batches = 2 MB (fits L2).
__global__ __launch_bounds__(256, 2)
void kD(const float* __restrict__ h, const float* __restrict__ s_i,
        const float* __restrict__ s_j, const int* __restrict__ topk,
        const float* __restrict__ gnn_bias,
        float* __restrict__ outp, float* __restrict__ acc){
  __shared__ float chs[DIM], chq[DIM];
  int t = threadIdx.x, wave = t >> 6, lane = t & 63;
  if (t < DIM){ chs[t] = 0.f; chq[t] = 0.f; }
  __syncthreads();
  int p = blockIdx.x;
  int xcd = p & 7, slot = p >> 3;            // 512 slots
  int b = xcd + 8*(slot >> 6);               // 8 batches per XCD
  int chunk = slot & 63;                     // 64 chunks of 16 rows
  int rs = lane >> 4, cg = lane & 15;
  int n = chunk*16 + wave*4 + rs;
  const float* hb  = h   + (size_t)b * NN * DIM;
  const float* sjb = s_j + (size_t)b * NN;
  float siv = s_i[(size_t)b*NN + n];
  int idx[KK];
  #pragma unroll
  for (int k = 0; k < KK; k++) idx[k] = topk[n*KK + k];
  float xv[KK];
  #pragma unroll
  for (int k = 0; k < KK; k++){
    float x = siv + sjb[idx[k]];
    xv[k] = (x > 0.f) ? x : SLOPE * x;
  }
  float m = xv[0];
  #pragma unroll
  for (int k = 1; k < KK; k++) m = fmaxf(m, xv[k]);
  float ssum = 0.f;
  #pragma unroll
  for (int k = 0; k < KK; k++){ xv[k] = __expf(xv[k] - m); ssum += xv[k]; }
  float rinv = 1.f / ssum;
  float4 gv[KK];
  #pragma unroll
  for (int k = 0; k < KK; k++) gv[k] = *(const float4*)(hb + idx[k]*DIM + cg*4);
  float4 o = {0.f,0.f,0.f,0.f};
  #pragma unroll
  for (int k = 0; k < KK; k++){
    float a = xv[k]*rinv;
    o.x += a*gv[k].x; o.y += a*gv[k].y; o.z += a*gv[k].z; o.w += a*gv[k].w;
  }
  float4 gb4 = *(const float4*)(gnn_bias + cg*4);
  o.x += gb4.x; o.y += gb4.y; o.z += gb4.z; o.w += gb4.w;
  *(float4*)(outp + ((size_t)b*NN + n)*DIM + cg*4) = o;
  int c0 = cg*4;
  atomicAdd(&chs[c0+0], o.x); atomicAdd(&chq[c0+0], o.x*o.x);
  atomicAdd(&chs[c0+1], o.y); atomicAdd(&chq[c0+1], o.y*o.y);
  atomicAdd(&chs[c0+2], o.z); atomicAdd(&chq[c0+2], o.z*o.z);
  atomicAdd(&chs[c0+3], o.w); atomicAdd(&chq[c0+3], o.w*o.w);
  __syncthreads();
  float* accr = acc + (p & (REPS-1))*128;
  if (t < DIM){ atomicAdd(&accr[t], chs[t]); atomicAdd(&accr[64+t], chq[t]); }
}

// ------- kF: reduce reps + BN1 apply + relu + *emb -> rep ; BN2 stats ----
__global__ void kF(const float* __restrict__ outp, const float* __restrict__ emb,
                   const float* __restrict__ acc, const float* __restrict__ bn1_g,
                   const float* __restrict__ bn1_b, float* __restrict__ rep,
                   float* __restrict__ acc2){
  __shared__ float chs[DIM], chq[DIM];
  int t = threadIdx.x;
  if (t < DIM){ chs[t] = 0.f; chq[t] = 0.f; }
  __syncthreads();
  int cbase = (t*4) & 63;
  float4 sm = {0,0,0,0}, sq = {0,0,0,0};
  #pragma unroll
  for (int rp = 0; rp < REPS; rp++){
    float4 a = *(const float4*)(acc + rp*128 + cbase);
    float4 b = *(const float4*)(acc + rp*128 + 64 + cbase);
    sm.x += a.x; sm.y += a.y; sm.z += a.z; sm.w += a.w;
    sq.x += b.x; sq.y += b.y; sq.z += b.z; sq.w += b.w;
  }
  float4 sc, bs;
  {
    const float inv = 1.f / BN_COUNT;
    float m0 = sm.x*inv, m1 = sm.y*inv, m2 = sm.z*inv, m3 = sm.w*inv;
    float v0 = sq.x*inv - m0*m0, v1 = sq.y*inv - m1*m1;
    float v2 = sq.z*inv - m2*m2, v3 = sq.w*inv - m3*m3;
    sc.x = bn1_g[cbase+0]*rsqrtf(v0+EPSV); sc.y = bn1_g[cbase+1]*rsqrtf(v1+EPSV);
    sc.z = bn1_g[cbase+2]*rsqrtf(v2+EPSV); sc.w = bn1_g[cbase+3]*rsqrtf(v3+EPSV);
    bs.x = bn1_b[cbase+0] - m0*sc.x; bs.y = bn1_b[cbase+1] - m1*sc.y;
    bs.z = bn1_b[cbase+2] - m2*sc.z; bs.w = bn1_b[cbase+3] - m3*sc.w;
  }
  float s0=0,s1=0,s2=0,s3=0,q0=0,q1=0,q2=0,q3=0;
  const float4* op4 = (const float4*)outp;
  const float4* em4 = (const float4*)emb;
  float4* rp4 = (float4*)rep;
  const int total = BB*NN*DIM/4;
  for (int e = blockIdx.x*256 + t; e < total; e += 2048*256){
    float4 x = op4[e];
    float4 em = em4[e & (NN*DIM/4 - 1)];
    float4 y;
    y.x = fmaxf(x.x*sc.x + bs.x, 0.f) * em.x;
    y.y = fmaxf(x.y*sc.y + bs.y, 0.f) * em.y;
    y.z = fmaxf(x.z*sc.z + bs.z, 0.f) * em.z;
    y.w = fmaxf(x.w*sc.w + bs.w, 0.f) * em.w;
    rp4[e] = y;
    s0 += y.x; q0 += y.x*y.x;
    s1 += y.y; q1 += y.y*y.y;
    s2 += y.z; q2 += y.z*y.z;
    s3 += y.w; q3 += y.w*y.w;
  }
  atomicAdd(&chs[cbase+0], s0); atomicAdd(&chq[cbase+0], q0);
  atomicAdd(&chs[cbase+1], s1); atomicAdd(&chq[cbase+1], q1);
  atomicAdd(&chs[cbase+2], s2); atomicAdd(&chq[cbase+2], q2);
  atomicAdd(&chs[cbase+3], s3); atomicAdd(&chq[cbase+3], q3);
  __syncthreads();
  float* acc2r = acc2 + (blockIdx.x & (REPS-1))*128;
  if (t < DIM){ atomicAdd(&acc2r[t], chs[t]); atomicAdd(&acc2r[64+t], chq[t]); }
}

// ------- kH: reduce reps + BN2 apply + relu + dot(out_w) -> fore ---------
__global__ void kH(const float* __restrict__ rep, const float* __restrict__ acc2,
                   const float* __restrict__ bn2_g, const float* __restrict__ bn2_b,
                   const float* __restrict__ out_w, const float* __restrict__ out_b,
                   float* __restrict__ out){
  int t = threadIdx.x, wave = t >> 6, lane = t & 63;
  int c16 = lane & 15, rsub = lane >> 4;
  int cb = c16*4;
  float4 sm = {0,0,0,0}, sq = {0,0,0,0};
  #pragma unroll
  for (int rp = 0; rp < REPS; rp++){
    float4 a = *(const float4*)(acc2 + rp*128 + cb);
    float4 b = *(const float4*)(acc2 + rp*128 + 64 + cb);
    sm.x += a.x; sm.y += a.y; sm.z += a.z; sm.w += a.w;
    sq.x += b.x; sq.y += b.y; sq.z += b.z; sq.w += b.w;
  }
  float4 sc, bs;
  {
    const float inv = 1.f / BN_COUNT;
    float m0 = sm.x*inv, m1 = sm.y*inv, m2 = sm.z*inv, m3 = sm.w*inv;
    float v0 = sq.x*inv - m0*m0, v1 = sq.y*inv - m1*m1;
    float v2 = sq.z*inv - m2*m2, v3 = sq.w*inv - m3*m3;
    sc.x = bn2_g[cb+0]*rsqrtf(v0+EPSV); sc.y = bn2_g[cb+1]*rsqrtf(v1+EPSV);
    sc.z = bn2_g[cb+2]*rsqrtf(v2+EPSV); sc.w = bn2_g[cb+3]*rsqrtf(v3+EPSV);
    bs.x = bn2_b[cb+0] - m0*sc.x; bs.y = bn2_b[cb+1] - m1*sc.y;
    bs.z = bn2_b[cb+2] - m2*sc.z; bs.w = bn2_b[cb+3] - m3*sc.w;
  }
  float4 w4 = *(const float4*)(out_w + cb);
  float ob = out_b[0];
  int rbase = blockIdx.x*64 + wave*16;
  for (int i = 0; i < 16; i += 4){
    int r = rbase + i + rsub;
    float4 x = *(const float4*)(rep + (size_t)r*DIM + cb);
    float p = fmaxf(x.x*sc.x + bs.x, 0.f) * w4.x
            + fmaxf(x.y*sc.y + bs.y, 0.f) * w4.y
            + fmaxf(x.z*sc.z + bs.z, 0.f) * w4.z
            + fmaxf(x.w*sc.w + bs.w, 0.f) * w4.w;
    p += __shfl_xor(p, 1, 64); p += __shfl_xor(p, 2, 64);
    p += __shfl_xor(p, 4, 64); p += __shfl_xor(p, 8, 64);
    if (c16 == 0) out[r] = p + ob;
  }
}

extern "C" void kernel_launch(void* const* d_in, const int* in_sizes, int n_in,
                              void* d_out, int out_size, void* d_ws, size_t ws_size,
                              hipStream_t stream) {
  const float* data     = (const float*)d_in[0];
  const float* emb      = (const float*)d_in[2];
  const float* lin_w    = (const float*)d_in[3];
  const float* att_i    = (const float*)d_in[4];
  const float* att_j    = (const float*)d_in[5];
  const float* att_em_i = (const float*)d_in[6];
  const float* att_em_j = (const float*)d_in[7];
  const float* gnn_bias = (const float*)d_in[8];
  const float* bn1_g    = (const float*)d_in[9];
  const float* bn1_b    = (const float*)d_in[10];
  const float* bn2_g    = (const float*)d_in[11];
  const float* bn2_b    = (const float*)d_in[12];
  const float* out_w    = (const float*)d_in[13];
  const float* out_b    = (const float*)d_in[14];
  float* out = (float*)d_out;

  float* ws   = (float*)d_ws;
  float* h    = ws;                        // 4194304 floats (aliased by rep)
  float* outp = ws + 4194304;              // 4194304
  float* s_i  = ws + 8388608;              // 65536
  float* s_j  = s_i + 65536;               // 65536
  float* inr  = s_j + 65536;               // 1024
  int*   topk = (int*)(inr + NN);          // 20480 ints
  float* acc1 = (float*)(topk + NN*KK);    // REPS*128 floats
  float* acc2 = acc1 + REPS*128;           // REPS*128 floats
  float* rep  = h;

  hipMemsetAsync(acc1, 0, 2*REPS*128*sizeof(float), stream);
  kA<<<NN, 64, 0, stream>>>(emb, inr);
  kB<<<NN, 256, 0, stream>>>(emb, inr, topk);
  kC<<<(BB*NN)/16, 256, 0, stream>>>(data, lin_w, att_i, att_j, att_em_i, att_em_j,
                                     emb, h, s_i, s_j);
  kD<<<(BB*NN)/16, 256, 0, stream>>>(h, s_i, s_j, topk, gnn_bias, outp, acc1);
  kF<<<2048, 256, 0, stream>>>(outp, emb, acc1, bn1_g, bn1_b, rep, acc2);
  kH<<<NN, 256, 0, stream>>>(rep, acc2, bn2_g, bn2_b, out_w, out_b, out);
}